// Round 9
// baseline (169.742 us; speedup 1.0000x reference)
//
#include <hip/hip_runtime.h>
#include <hip/hip_bf16.h>
#include <math.h>

#define B_N 2048
#define V_N 5023
#define V3_N 15069
#define NSJB 157
#define CHUNK 32

typedef float f32x4 __attribute__((ext_vector_type(4)));
typedef short short8 __attribute__((ext_vector_type(8)));

static __device__ __forceinline__ ushort f2bf(float f) {
  __hip_bfloat16 h = __float2bfloat16(f);
  return *reinterpret_cast<ushort*>(&h);
}

// ---------------- K1: partial SJ[j][c] = sum_v Jr[j,v] * col_c(v) ----------------
__global__ __launch_bounds__(256) void k_sj_part(const float* __restrict__ sdirs,
                                                 const float* __restrict__ vtemp,
                                                 const float* __restrict__ Jr,
                                                 float* __restrict__ part) {
  __shared__ float JrL[5][CHUNK];
  int t = threadIdx.x, bk = blockIdx.x;
  int vstart = bk * CHUNK;
  int cnt = min(CHUNK, V_N - vstart);
  for (int idx = t; idx < 5 * CHUNK; idx += 256) {
    int j = idx / CHUNK, vi = idx % CHUNK;
    JrL[j][vi] = (vi < cnt) ? Jr[j * V_N + vstart + vi] : 0.0f;
  }
  __syncthreads();
  float acc0[5] = {0, 0, 0, 0, 0}, acc1[5] = {0, 0, 0, 0, 0};
  int c0 = t, c1 = t + 256;
#pragma unroll 4
  for (int vi = 0; vi < CHUNK; ++vi) {
    int v = min(vstart + vi, V_N - 1);
    float val0 = sdirs[(size_t)v * 450 + c0];
    float val1 = 0.0f;
    if (c1 < 450) val1 = sdirs[(size_t)v * 450 + c1];
    else if (c1 < 453) val1 = vtemp[(size_t)v * 3 + (c1 - 450)];
#pragma unroll
    for (int j = 0; j < 5; ++j) {
      float w = JrL[j][vi];
      acc0[j] = fmaf(w, val0, acc0[j]);
      acc1[j] = fmaf(w, val1, acc1[j]);
    }
  }
  float* prow = part + (size_t)bk * 2280;
#pragma unroll
  for (int j = 0; j < 5; ++j) {
    prow[j * 456 + c0] = acc0[j];
    if (c1 < 453) prow[j * 456 + c1] = acc1[j];
  }
}

__global__ void k_sj_reduce(const float* __restrict__ part, float* __restrict__ SJ) {
  int id = blockIdx.x * 256 + threadIdx.x;
  if (id >= 2280) return;
  int c = id % 456;
  if (c >= 453) return;
  float s = 0.0f;
  for (int bk = 0; bk < NSJB; ++bk) s += part[(size_t)bk * 2280 + id];
  SJ[id] = s;
}

// ---------------- fill bb (bf16 coefficients) for cols 0..149, zero 150..191 ----------------
__global__ void k_bext_bf(const float* __restrict__ shp, const float* __restrict__ expr,
                          ushort* __restrict__ bb) {
  int idx = blockIdx.x * 256 + threadIdx.x;  // 2048*96 uints
  int b = idx / 96, cp = idx - b * 96;
  int c0 = cp * 2;
  float f0 = 0.0f, f1 = 0.0f;
  if (c0 < 100) {
    f0 = shp[(size_t)b * 100 + c0];
    f1 = shp[(size_t)b * 100 + c0 + 1];
  } else if (c0 < 150) {
    f0 = expr[(size_t)b * 50 + (c0 - 100)];
    f1 = expr[(size_t)b * 50 + (c0 - 99)];
  }
  ((uint*)bb)[idx] = (uint)f2bf(f0) | ((uint)f2bf(f1) << 16);
}

// ---------------- Rodrigues + Jts (fused) + chain; bf16 pose-features + delta-form A ----------------
// A row layout per batch (64 floats): [0..11]=A0, [j*12..j*12+11]=Aj-A0 (j=1..4)
__global__ void k_pose(const float* __restrict__ pose, const float* __restrict__ shp,
                       const float* __restrict__ expr, const float* __restrict__ SJ,
                       ushort* __restrict__ bb, float* __restrict__ A,
                       float* __restrict__ out) {
  int b = blockIdx.x * 256 + threadIdx.x;
  if (b >= B_N) return;
  float R[5][3][3];
#pragma unroll
  for (int j = 0; j < 5; ++j) {
    float rx = pose[(size_t)b * 15 + j * 3 + 0];
    float ry = pose[(size_t)b * 15 + j * 3 + 1];
    float rz = pose[(size_t)b * 15 + j * 3 + 2];
    float sx = rx + 1e-8f, sy = ry + 1e-8f, sz = rz + 1e-8f;
    float ang = sqrtf(sx * sx + sy * sy + sz * sz);
    float inv = 1.0f / ang;
    float ux = rx * inv, uy = ry * inv, uz = rz * inv;
    float c = cosf(ang), s = sinf(ang), omc = 1.0f - c;
    float K[3][3] = {{0.0f, -uz, uy}, {uz, 0.0f, -ux}, {-uy, ux, 0.0f}};
#pragma unroll
    for (int m = 0; m < 3; ++m)
#pragma unroll
      for (int n = 0; n < 3; ++n) {
        float k2 = 0.0f;
#pragma unroll
        for (int q = 0; q < 3; ++q) k2 += K[m][q] * K[q][n];
        R[j][m][n] = ((m == n) ? 1.0f : 0.0f) + s * K[m][n] + omc * k2;
      }
  }
  // pose features (bf16) -> bb cols 150..185
  {
    float pf[36];
#pragma unroll
    for (int j = 1; j < 5; ++j)
#pragma unroll
      for (int m = 0; m < 3; ++m)
#pragma unroll
        for (int n = 0; n < 3; ++n)
          pf[(j - 1) * 9 + m * 3 + n] = R[j][m][n] - ((m == n) ? 1.0f : 0.0f);
    uint* bbu = (uint*)bb + (size_t)b * 96 + 75;
#pragma unroll
    for (int q = 0; q < 18; ++q)
      bbu[q] = (uint)f2bf(pf[2 * q]) | ((uint)f2bf(pf[2 * q + 1]) << 16);
  }
  // Jts fused: Jt[j][k] = SJ[j][450+k] + sum_l betas[l]*SJ[j][k*150+l]
  float Jt[5][3];
  {
    const float* srow = shp + (size_t)b * 100;
    const float* erow = expr + (size_t)b * 50;
#pragma unroll
    for (int j = 0; j < 5; ++j) {
      const float* SJr = SJ + j * 456;
#pragma unroll
      for (int k = 0; k < 3; ++k) {
        float acc = SJr[450 + k];
        for (int l = 0; l < 100; ++l) acc = fmaf(srow[l], SJr[k * 150 + l], acc);
        for (int l = 0; l < 50; ++l) acc = fmaf(erow[l], SJr[k * 150 + 100 + l], acc);
        Jt[j][k] = acc;
      }
    }
  }
  const int par[5] = {0, 0, 1, 1, 1};
  float rel[5][3];
#pragma unroll
  for (int k = 0; k < 3; ++k) rel[0][k] = Jt[0][k];
#pragma unroll
  for (int j = 1; j < 5; ++j)
#pragma unroll
    for (int k = 0; k < 3; ++k) rel[j][k] = Jt[j][k] - Jt[par[j]][k];
  float Rg[5][3][3], tg[5][3];
#pragma unroll
  for (int m = 0; m < 3; ++m) {
#pragma unroll
    for (int n = 0; n < 3; ++n) Rg[0][m][n] = R[0][m][n];
    tg[0][m] = rel[0][m];
  }
#pragma unroll
  for (int j = 1; j < 5; ++j) {
    int p = par[j];
#pragma unroll
    for (int m = 0; m < 3; ++m) {
      float t = tg[p][m];
#pragma unroll
      for (int n = 0; n < 3; ++n) {
        float s = 0.0f;
#pragma unroll
        for (int q = 0; q < 3; ++q) s = fmaf(Rg[p][m][q], R[j][q][n], s);
        Rg[j][m][n] = s;
        t = fmaf(Rg[p][m][n], rel[j][n], t);
      }
      tg[j][m] = t;
    }
  }
#pragma unroll
  for (int j = 0; j < 5; ++j)
#pragma unroll
    for (int k = 0; k < 3; ++k)
      out[(size_t)B_N * V_N * 3 + ((size_t)b * 5 + j) * 3 + k] = tg[j][k];
  float Af[5][12];
#pragma unroll
  for (int j = 0; j < 5; ++j)
#pragma unroll
    for (int m = 0; m < 3; ++m) {
      float tj = 0.0f;
#pragma unroll
      for (int n = 0; n < 3; ++n) {
        Af[j][m * 4 + n] = Rg[j][m][n];
        tj = fmaf(Rg[j][m][n], Jt[j][n], tj);
      }
      Af[j][m * 4 + 3] = tg[j][m] - tj;
    }
  float* Ab = A + (size_t)b * 64;
#pragma unroll
  for (int q = 0; q < 12; ++q) Ab[q] = Af[0][q];
#pragma unroll
  for (int j = 1; j < 5; ++j)
#pragma unroll
    for (int q = 0; q < 12; ++q) Ab[j * 12 + q] = Af[j][q] - Af[0][q];
}

// ---------------- build bf16 basis [M4][192] ----------------
__global__ __launch_bounds__(256) void k_basis(const float* __restrict__ sdirs,
                                               const float* __restrict__ pdirs,
                                               ushort* __restrict__ basis) {
  __shared__ float Sh[16][452];
  __shared__ float Pd[36][48];
  int t = threadIdx.x, bx = blockIdx.x;
  int v0 = bx * 16;
  for (int idx = t; idx < 16 * 450; idx += 256) {
    int r = idx / 450, c = idx - r * 450;
    int v = v0 + r;
    Sh[r][c] = (v < V_N) ? sdirs[(size_t)v * 450 + c] : 0.0f;
  }
  for (int idx = t; idx < 36 * 48; idx += 256) {
    int p = idx / 48, c = idx - p * 48;
    int v3 = v0 * 3 + c;
    Pd[p][c] = (v3 < V3_N) ? pdirs[(size_t)p * V3_N + v3] : 0.0f;
  }
  __syncthreads();
  for (int idx = t; idx < 64 * 96; idx += 256) {
    int row = idx / 96, kp = idx - row * 96;
    int vl = row >> 2, c = row & 3;
    int k0 = kp * 2;
    float f0 = 0.0f, f1 = 0.0f;
    if (c < 3) {
      if (k0 < 150) {
        f0 = Sh[vl][c * 150 + k0];
        f1 = Sh[vl][c * 150 + k0 + 1];
      } else if (k0 < 186) {
        f0 = Pd[k0 - 150][vl * 3 + c];
        f1 = Pd[k0 - 149][vl * 3 + c];
      }
    }
    uint u = (uint)f2bf(f0) | ((uint)f2bf(f1) << 16);
    ((uint*)basis)[(size_t)(bx * 64 + row) * 96 + kp] = u;
  }
}

// ---------------- main: MFMA GEMM + fused skinning (AmL LDS epilogue, batch-fast grid) ----------------
// grid (32 batch-tiles FAST, 314 vertex-tiles slow). 8 waves: 4(M) x 2(N).
__global__ __launch_bounds__(512, 4) void k_main(const ushort* __restrict__ basis,
                                                 const ushort* __restrict__ bb,
                                                 const float* __restrict__ Amat,
                                                 const float* __restrict__ lw,
                                                 const float* __restrict__ vtemp,
                                                 float* __restrict__ out) {
  __shared__ alignas(16) ushort AL[64 * 200];
  __shared__ alignas(16) ushort BL[64 * 200];
  __shared__ alignas(16) float AmL[64 * 68];  // delta-form rel transforms
  int t = threadIdx.x;
  int bx = blockIdx.y;  // vertex tile (slow)
  int by = blockIdx.x;  // batch tile (fast -> basis tile L2-reused by 32 blocks)
  int b0 = by * 64;
#pragma unroll
  for (int i = 0; i < 3; ++i) {
    int c = t + i * 512;
    int r = c / 24, k = (c % 24) * 8;
    *(short8*)(&AL[r * 200 + k]) = *(const short8*)(&basis[((size_t)bx * 64 + r) * 192 + k]);
    *(short8*)(&BL[r * 200 + k]) = *(const short8*)(&bb[((size_t)(b0 + r)) * 192 + k]);
  }
#pragma unroll
  for (int i = 0; i < 2; ++i) {
    int c = t + i * 512;
    int r = c / 16, q = (c % 16) * 4;
    *(f32x4*)(&AmL[r * 68 + q]) = *(const f32x4*)(&Amat[((size_t)(b0 + r)) * 64 + q]);
  }
  __syncthreads();
  int lane = t & 63;
  int w = __builtin_amdgcn_readfirstlane(t >> 6);
  int wm = w >> 1, wn = w & 1;
  int lm = lane & 15, g = lane >> 4;
  f32x4 acc0 = {0.f, 0.f, 0.f, 0.f}, acc1 = {0.f, 0.f, 0.f, 0.f};
  const int arow = (wm * 16 + lm) * 200;
  const int brow0 = (wn * 32 + lm) * 200;
  const int brow1 = (wn * 32 + 16 + lm) * 200;
#pragma unroll
  for (int ks = 0; ks < 6; ++ks) {
    int k = ks * 32 + 8 * g;
    short8 af = *(const short8*)(&AL[arow + k]);
    short8 bf0 = *(const short8*)(&BL[brow0 + k]);
    short8 bf1 = *(const short8*)(&BL[brow1 + k]);
    acc0 = __builtin_amdgcn_mfma_f32_16x16x32_bf16(af, bf0, acc0, 0, 0, 0);
    acc1 = __builtin_amdgcn_mfma_f32_16x16x32_bf16(af, bf1, acc1, 0, 0, 0);
  }
  int v = bx * 16 + wm * 4 + g;
  bool valid = v < V_N;
  int vv = valid ? v : 0;
  float wv[4];
#pragma unroll
  for (int j = 0; j < 4; ++j) wv[j] = lw[(size_t)vv * 5 + 1 + j];
  float vt0 = vtemp[(size_t)vv * 3 + 0];
  float vt1 = vtemp[(size_t)vv * 3 + 1];
  float vt2 = vtemp[(size_t)vv * 3 + 2];
#pragma unroll
  for (int ni = 0; ni < 2; ++ni) {
    f32x4 p = ni ? acc1 : acc0;
    int bl = wn * 32 + ni * 16 + lm;
    const float* Ar = &AmL[bl * 68];
    f32x4 T0 = *(const f32x4*)(Ar + 0);
    f32x4 T1 = *(const f32x4*)(Ar + 4);
    f32x4 T2 = *(const f32x4*)(Ar + 8);
#pragma unroll
    for (int j = 1; j < 5; ++j) {
      f32x4 d0 = *(const f32x4*)(Ar + j * 12 + 0);
      f32x4 d1 = *(const f32x4*)(Ar + j * 12 + 4);
      f32x4 d2 = *(const f32x4*)(Ar + j * 12 + 8);
      float wjv = wv[j - 1];
#pragma unroll
      for (int c = 0; c < 4; ++c) {
        T0[c] = fmaf(wjv, d0[c], T0[c]);
        T1[c] = fmaf(wjv, d1[c], T1[c]);
        T2[c] = fmaf(wjv, d2[c], T2[c]);
      }
    }
    float x = p[0] + vt0, y = p[1] + vt1, z = p[2] + vt2;
    float ox = fmaf(T0[0], x, fmaf(T0[1], y, fmaf(T0[2], z, T0[3])));
    float oy = fmaf(T1[0], x, fmaf(T1[1], y, fmaf(T1[2], z, T1[3])));
    float oz = fmaf(T2[0], x, fmaf(T2[1], y, fmaf(T2[2], z, T2[3])));
    if (valid) {
      size_t o = ((size_t)(b0 + bl)) * V3_N + (size_t)v * 3;
      out[o + 0] = ox;
      out[o + 1] = oy;
      out[o + 2] = oz;
    }
  }
}

extern "C" void kernel_launch(void* const* d_in, const int* in_sizes, int n_in,
                              void* d_out, int out_size, void* d_ws, size_t ws_size,
                              hipStream_t stream) {
  const float* shp = (const float*)d_in[0];
  const float* expr = (const float*)d_in[1];
  const float* pose = (const float*)d_in[2];
  const float* vtemp = (const float*)d_in[3];
  const float* sdirs = (const float*)d_in[4];
  const float* pdirs = (const float*)d_in[5];
  const float* Jr = (const float*)d_in[6];
  const float* lw = (const float*)d_in[7];
  float* out = (float*)d_out;
  float* wsf = (float*)d_ws;

  // workspace layout (float slots)
  const size_t OFF_PART = 0;         // 157*2280 = 357,960
  const size_t OFF_SJ = 358400;      // 2,280
  const size_t OFF_A = 786688;       // 131,072
  const size_t OFF_BB = 917760;      // bf16 2048*192 -> 196,608 f32 slots
  const size_t OFF_BASIS = 1114368;  // bf16 20096*192 -> 1,929,216 f32 slots (ends 3,043,584)
  float* part = wsf + OFF_PART;
  float* SJ = wsf + OFF_SJ;
  float* A = wsf + OFF_A;
  ushort* bb = (ushort*)(wsf + OFF_BB);
  ushort* basis = (ushort*)(wsf + OFF_BASIS);

  hipLaunchKernelGGL(k_basis, dim3(314), dim3(256), 0, stream, sdirs, pdirs, basis);
  hipLaunchKernelGGL(k_sj_part, dim3(NSJB), dim3(256), 0, stream, sdirs, vtemp, Jr, part);
  hipLaunchKernelGGL(k_sj_reduce, dim3(9), dim3(256), 0, stream, part, SJ);
  hipLaunchKernelGGL(k_bext_bf, dim3(768), dim3(256), 0, stream, shp, expr, bb);
  hipLaunchKernelGGL(k_pose, dim3(8), dim3(256), 0, stream, pose, shp, expr, SJ, bb, A, out);
  hipLaunchKernelGGL(k_main, dim3(32, 314), dim3(512), 0, stream,
                     basis, bb, A, lw, vtemp, out);
}

// Round 10
// 140.266 us; speedup vs baseline: 1.2101x; 1.2101x over previous
//
#include <hip/hip_runtime.h>
#include <hip/hip_bf16.h>
#include <math.h>

#define B_N 2048
#define V_N 5023
#define V3_N 15069
#define NSJB 157
#define CHUNK 32

typedef float f32x4 __attribute__((ext_vector_type(4)));
typedef short short8 __attribute__((ext_vector_type(8)));

static __device__ __forceinline__ ushort f2bf(float f) {
  __hip_bfloat16 h = __float2bfloat16(f);
  return *reinterpret_cast<ushort*>(&h);
}

// ---------------- K1: partial SJ[j][c] = sum_v Jr[j,v] * col_c(v) ----------------
__global__ __launch_bounds__(256) void k_sj_part(const float* __restrict__ sdirs,
                                                 const float* __restrict__ vtemp,
                                                 const float* __restrict__ Jr,
                                                 float* __restrict__ part) {
  __shared__ float JrL[5][CHUNK];
  int t = threadIdx.x, bk = blockIdx.x;
  int vstart = bk * CHUNK;
  int cnt = min(CHUNK, V_N - vstart);
  for (int idx = t; idx < 5 * CHUNK; idx += 256) {
    int j = idx / CHUNK, vi = idx % CHUNK;
    JrL[j][vi] = (vi < cnt) ? Jr[j * V_N + vstart + vi] : 0.0f;
  }
  __syncthreads();
  float acc0[5] = {0, 0, 0, 0, 0}, acc1[5] = {0, 0, 0, 0, 0};
  int c0 = t, c1 = t + 256;
#pragma unroll 4
  for (int vi = 0; vi < CHUNK; ++vi) {
    int v = min(vstart + vi, V_N - 1);
    float val0 = sdirs[(size_t)v * 450 + c0];
    float val1 = 0.0f;
    if (c1 < 450) val1 = sdirs[(size_t)v * 450 + c1];
    else if (c1 < 453) val1 = vtemp[(size_t)v * 3 + (c1 - 450)];
#pragma unroll
    for (int j = 0; j < 5; ++j) {
      float w = JrL[j][vi];
      acc0[j] = fmaf(w, val0, acc0[j]);
      acc1[j] = fmaf(w, val1, acc1[j]);
    }
  }
  float* prow = part + (size_t)bk * 2280;
#pragma unroll
  for (int j = 0; j < 5; ++j) {
    prow[j * 456 + c0] = acc0[j];
    if (c1 < 453) prow[j * 456 + c1] = acc1[j];
  }
}

__global__ void k_sj_reduce(const float* __restrict__ part, float* __restrict__ SJ) {
  int id = blockIdx.x * 256 + threadIdx.x;
  if (id >= 2280) return;
  int c = id % 456;
  if (c >= 453) return;
  float s = 0.0f;
  for (int bk = 0; bk < NSJB; ++bk) s += part[(size_t)bk * 2280 + id];
  SJ[id] = s;
}

// ---------------- Jts[b,j,k] (separate, 15-way parallel per batch) ----------------
__global__ void k_jts(const float* __restrict__ shp, const float* __restrict__ expr,
                      const float* __restrict__ SJ, float* __restrict__ Jts) {
  int gid = blockIdx.x * 256 + threadIdx.x;
  int b = gid >> 4, jk = gid & 15;
  if (b >= B_N || jk >= 15) return;
  int j = jk / 3, k = jk - j * 3;
  const float* SJr = SJ + j * 456;
  float acc = SJr[450 + k];
  const float* srow = shp + (size_t)b * 100;
  const float* erow = expr + (size_t)b * 50;
  for (int l = 0; l < 100; ++l) acc = fmaf(srow[l], SJr[k * 150 + l], acc);
  for (int l = 0; l < 50; ++l) acc = fmaf(erow[l], SJr[k * 150 + 100 + l], acc);
  Jts[(size_t)b * 16 + jk] = acc;
}

// ---------------- fill bb (bf16 coefficients) for cols 0..149, zero 150..191 ----------------
__global__ void k_bext_bf(const float* __restrict__ shp, const float* __restrict__ expr,
                          ushort* __restrict__ bb) {
  int idx = blockIdx.x * 256 + threadIdx.x;  // 2048*96 uints
  int b = idx / 96, cp = idx - b * 96;
  int c0 = cp * 2;
  float f0 = 0.0f, f1 = 0.0f;
  if (c0 < 100) {
    f0 = shp[(size_t)b * 100 + c0];
    f1 = shp[(size_t)b * 100 + c0 + 1];
  } else if (c0 < 150) {
    f0 = expr[(size_t)b * 50 + (c0 - 100)];
    f1 = expr[(size_t)b * 50 + (c0 - 99)];
  }
  ((uint*)bb)[idx] = (uint)f2bf(f0) | ((uint)f2bf(f1) << 16);
}

// ---------------- Rodrigues + chain; bf16 pose-features + delta-form A ----------------
// A row layout per batch (64 floats): [0..11]=A0, [j*12..j*12+11]=Aj-A0 (j=1..4)
__global__ void k_pose(const float* __restrict__ pose, const float* __restrict__ Jts,
                       ushort* __restrict__ bb, float* __restrict__ A,
                       float* __restrict__ out) {
  int b = blockIdx.x * 256 + threadIdx.x;
  if (b >= B_N) return;
  float R[5][3][3];
#pragma unroll
  for (int j = 0; j < 5; ++j) {
    float rx = pose[(size_t)b * 15 + j * 3 + 0];
    float ry = pose[(size_t)b * 15 + j * 3 + 1];
    float rz = pose[(size_t)b * 15 + j * 3 + 2];
    float sx = rx + 1e-8f, sy = ry + 1e-8f, sz = rz + 1e-8f;
    float ang = sqrtf(sx * sx + sy * sy + sz * sz);
    float inv = 1.0f / ang;
    float ux = rx * inv, uy = ry * inv, uz = rz * inv;
    float c = cosf(ang), s = sinf(ang), omc = 1.0f - c;
    float K[3][3] = {{0.0f, -uz, uy}, {uz, 0.0f, -ux}, {-uy, ux, 0.0f}};
#pragma unroll
    for (int m = 0; m < 3; ++m)
#pragma unroll
      for (int n = 0; n < 3; ++n) {
        float k2 = 0.0f;
#pragma unroll
        for (int q = 0; q < 3; ++q) k2 += K[m][q] * K[q][n];
        R[j][m][n] = ((m == n) ? 1.0f : 0.0f) + s * K[m][n] + omc * k2;
      }
  }
  // pose features (bf16) -> bb cols 150..185
  {
    float pf[36];
#pragma unroll
    for (int j = 1; j < 5; ++j)
#pragma unroll
      for (int m = 0; m < 3; ++m)
#pragma unroll
        for (int n = 0; n < 3; ++n)
          pf[(j - 1) * 9 + m * 3 + n] = R[j][m][n] - ((m == n) ? 1.0f : 0.0f);
    uint* bbu = (uint*)bb + (size_t)b * 96 + 75;
#pragma unroll
    for (int q = 0; q < 18; ++q)
      bbu[q] = (uint)f2bf(pf[2 * q]) | ((uint)f2bf(pf[2 * q + 1]) << 16);
  }
  float Jt[5][3];
#pragma unroll
  for (int j = 0; j < 5; ++j)
#pragma unroll
    for (int k = 0; k < 3; ++k) Jt[j][k] = Jts[(size_t)b * 16 + j * 3 + k];
  const int par[5] = {0, 0, 1, 1, 1};
  float rel[5][3];
#pragma unroll
  for (int k = 0; k < 3; ++k) rel[0][k] = Jt[0][k];
#pragma unroll
  for (int j = 1; j < 5; ++j)
#pragma unroll
    for (int k = 0; k < 3; ++k) rel[j][k] = Jt[j][k] - Jt[par[j]][k];
  float Rg[5][3][3], tg[5][3];
#pragma unroll
  for (int m = 0; m < 3; ++m) {
#pragma unroll
    for (int n = 0; n < 3; ++n) Rg[0][m][n] = R[0][m][n];
    tg[0][m] = rel[0][m];
  }
#pragma unroll
  for (int j = 1; j < 5; ++j) {
    int p = par[j];
#pragma unroll
    for (int m = 0; m < 3; ++m) {
      float t = tg[p][m];
#pragma unroll
      for (int n = 0; n < 3; ++n) {
        float s = 0.0f;
#pragma unroll
        for (int q = 0; q < 3; ++q) s = fmaf(Rg[p][m][q], R[j][q][n], s);
        Rg[j][m][n] = s;
        t = fmaf(Rg[p][m][n], rel[j][n], t);
      }
      tg[j][m] = t;
    }
  }
#pragma unroll
  for (int j = 0; j < 5; ++j)
#pragma unroll
    for (int k = 0; k < 3; ++k)
      out[(size_t)B_N * V_N * 3 + ((size_t)b * 5 + j) * 3 + k] = tg[j][k];
  float Af[5][12];
#pragma unroll
  for (int j = 0; j < 5; ++j)
#pragma unroll
    for (int m = 0; m < 3; ++m) {
      float tj = 0.0f;
#pragma unroll
      for (int n = 0; n < 3; ++n) {
        Af[j][m * 4 + n] = Rg[j][m][n];
        tj = fmaf(Rg[j][m][n], Jt[j][n], tj);
      }
      Af[j][m * 4 + 3] = tg[j][m] - tj;
    }
  float* Ab = A + (size_t)b * 64;
#pragma unroll
  for (int q = 0; q < 12; ++q) Ab[q] = Af[0][q];
#pragma unroll
  for (int j = 1; j < 5; ++j)
#pragma unroll
    for (int q = 0; q < 12; ++q) Ab[j * 12 + q] = Af[j][q] - Af[0][q];
}

// ---------------- build bf16 basis [M4][192] ----------------
__global__ __launch_bounds__(256) void k_basis(const float* __restrict__ sdirs,
                                               const float* __restrict__ pdirs,
                                               ushort* __restrict__ basis) {
  __shared__ float Sh[16][452];
  __shared__ float Pd[36][48];
  int t = threadIdx.x, bx = blockIdx.x;
  int v0 = bx * 16;
  for (int idx = t; idx < 16 * 450; idx += 256) {
    int r = idx / 450, c = idx - r * 450;
    int v = v0 + r;
    Sh[r][c] = (v < V_N) ? sdirs[(size_t)v * 450 + c] : 0.0f;
  }
  for (int idx = t; idx < 36 * 48; idx += 256) {
    int p = idx / 48, c = idx - p * 48;
    int v3 = v0 * 3 + c;
    Pd[p][c] = (v3 < V3_N) ? pdirs[(size_t)p * V3_N + v3] : 0.0f;
  }
  __syncthreads();
  for (int idx = t; idx < 64 * 96; idx += 256) {
    int row = idx / 96, kp = idx - row * 96;
    int vl = row >> 2, c = row & 3;
    int k0 = kp * 2;
    float f0 = 0.0f, f1 = 0.0f;
    if (c < 3) {
      if (k0 < 150) {
        f0 = Sh[vl][c * 150 + k0];
        f1 = Sh[vl][c * 150 + k0 + 1];
      } else if (k0 < 186) {
        f0 = Pd[k0 - 150][vl * 3 + c];
        f1 = Pd[k0 - 149][vl * 3 + c];
      }
    }
    uint u = (uint)f2bf(f0) | ((uint)f2bf(f1) << 16);
    ((uint*)basis)[(size_t)(bx * 64 + row) * 96 + kp] = u;
  }
}

// ---------------- main: MFMA GEMM + fused skinning + coalesced store epilogue ----------------
// grid (32 batch-tiles FAST, 314 vertex-tiles slow). 8 waves: 4(M) x 2(N).
__global__ __launch_bounds__(512, 4) void k_main(const ushort* __restrict__ basis,
                                                 const ushort* __restrict__ bb,
                                                 const float* __restrict__ Amat,
                                                 const float* __restrict__ lw,
                                                 const float* __restrict__ vtemp,
                                                 float* __restrict__ out) {
  __shared__ alignas(16) ushort AL[64 * 200];  // basis tile; reused as OutL after MFMA
  __shared__ alignas(16) ushort BL[64 * 200];
  __shared__ alignas(16) float AmL[64 * 68];   // delta-form rel transforms
  float* OutL = (float*)AL;                    // [64 batch rows][50] (48 used + pad)
  int t = threadIdx.x;
  int bx = blockIdx.y;  // vertex tile (slow)
  int by = blockIdx.x;  // batch tile (fast -> basis tile L2-reused by 32 blocks)
  int b0 = by * 64;
#pragma unroll
  for (int i = 0; i < 3; ++i) {
    int c = t + i * 512;
    int r = c / 24, k = (c % 24) * 8;
    *(short8*)(&AL[r * 200 + k]) = *(const short8*)(&basis[((size_t)bx * 64 + r) * 192 + k]);
    *(short8*)(&BL[r * 200 + k]) = *(const short8*)(&bb[((size_t)(b0 + r)) * 192 + k]);
  }
#pragma unroll
  for (int i = 0; i < 2; ++i) {
    int c = t + i * 512;
    int r = c / 16, q = (c % 16) * 4;
    *(f32x4*)(&AmL[r * 68 + q]) = *(const f32x4*)(&Amat[((size_t)(b0 + r)) * 64 + q]);
  }
  __syncthreads();
  int lane = t & 63;
  int w = __builtin_amdgcn_readfirstlane(t >> 6);
  int wm = w >> 1, wn = w & 1;
  int lm = lane & 15, g = lane >> 4;
  f32x4 acc0 = {0.f, 0.f, 0.f, 0.f}, acc1 = {0.f, 0.f, 0.f, 0.f};
  const int arow = (wm * 16 + lm) * 200;
  const int brow0 = (wn * 32 + lm) * 200;
  const int brow1 = (wn * 32 + 16 + lm) * 200;
#pragma unroll
  for (int ks = 0; ks < 6; ++ks) {
    int k = ks * 32 + 8 * g;
    short8 af = *(const short8*)(&AL[arow + k]);
    short8 bf0 = *(const short8*)(&BL[brow0 + k]);
    short8 bf1 = *(const short8*)(&BL[brow1 + k]);
    acc0 = __builtin_amdgcn_mfma_f32_16x16x32_bf16(af, bf0, acc0, 0, 0, 0);
    acc1 = __builtin_amdgcn_mfma_f32_16x16x32_bf16(af, bf1, acc1, 0, 0, 0);
  }
  int v = bx * 16 + wm * 4 + g;
  int vv = v < V_N ? v : 0;
  float wv[4];
#pragma unroll
  for (int j = 0; j < 4; ++j) wv[j] = lw[(size_t)vv * 5 + 1 + j];
  float vt0 = vtemp[(size_t)vv * 3 + 0];
  float vt1 = vtemp[(size_t)vv * 3 + 1];
  float vt2 = vtemp[(size_t)vv * 3 + 2];
  __syncthreads();  // all MFMA reads of AL done; AL now reusable as OutL
#pragma unroll
  for (int ni = 0; ni < 2; ++ni) {
    f32x4 p = ni ? acc1 : acc0;
    int bl = wn * 32 + ni * 16 + lm;
    const float* Ar = &AmL[bl * 68];
    f32x4 T0 = *(const f32x4*)(Ar + 0);
    f32x4 T1 = *(const f32x4*)(Ar + 4);
    f32x4 T2 = *(const f32x4*)(Ar + 8);
#pragma unroll
    for (int j = 1; j < 5; ++j) {
      f32x4 d0 = *(const f32x4*)(Ar + j * 12 + 0);
      f32x4 d1 = *(const f32x4*)(Ar + j * 12 + 4);
      f32x4 d2 = *(const f32x4*)(Ar + j * 12 + 8);
      float wjv = wv[j - 1];
#pragma unroll
      for (int c = 0; c < 4; ++c) {
        T0[c] = fmaf(wjv, d0[c], T0[c]);
        T1[c] = fmaf(wjv, d1[c], T1[c]);
        T2[c] = fmaf(wjv, d2[c], T2[c]);
      }
    }
    float x = p[0] + vt0, y = p[1] + vt1, z = p[2] + vt2;
    float ox = fmaf(T0[0], x, fmaf(T0[1], y, fmaf(T0[2], z, T0[3])));
    float oy = fmaf(T1[0], x, fmaf(T1[1], y, fmaf(T1[2], z, T1[3])));
    float oz = fmaf(T2[0], x, fmaf(T2[1], y, fmaf(T2[2], z, T2[3])));
    int vi = wm * 4 + g;
    OutL[bl * 50 + vi * 3 + 0] = ox;
    OutL[bl * 50 + vi * 3 + 1] = oy;
    OutL[bl * 50 + vi * 3 + 2] = oz;
  }
  __syncthreads();
  // cooperative coalesced store: 64 batch rows x 48 contiguous floats
  const int v3base = bx * 48;  // = v0 * 3
#pragma unroll
  for (int i = 0; i < 6; ++i) {
    int d = t + i * 512;  // 0..3071
    int row = d / 48, col = d - row * 48;
    if (v3base + col < V3_N)
      out[(size_t)(b0 + row) * V3_N + v3base + col] = OutL[row * 50 + col];
  }
}

extern "C" void kernel_launch(void* const* d_in, const int* in_sizes, int n_in,
                              void* d_out, int out_size, void* d_ws, size_t ws_size,
                              hipStream_t stream) {
  const float* shp = (const float*)d_in[0];
  const float* expr = (const float*)d_in[1];
  const float* pose = (const float*)d_in[2];
  const float* vtemp = (const float*)d_in[3];
  const float* sdirs = (const float*)d_in[4];
  const float* pdirs = (const float*)d_in[5];
  const float* Jr = (const float*)d_in[6];
  const float* lw = (const float*)d_in[7];
  float* out = (float*)d_out;
  float* wsf = (float*)d_ws;

  // workspace layout (float slots)
  const size_t OFF_PART = 0;         // 157*2280 = 357,960
  const size_t OFF_SJ = 358400;      // 2,280
  const size_t OFF_JTS = 753920;     // 32,768
  const size_t OFF_A = 786688;       // 131,072
  const size_t OFF_BB = 917760;      // bf16 2048*192 -> 196,608 f32 slots
  const size_t OFF_BASIS = 1114368;  // bf16 20096*192 -> 1,929,216 f32 slots (ends 3,043,584)
  float* part = wsf + OFF_PART;
  float* SJ = wsf + OFF_SJ;
  float* Jts = wsf + OFF_JTS;
  float* A = wsf + OFF_A;
  ushort* bb = (ushort*)(wsf + OFF_BB);
  ushort* basis = (ushort*)(wsf + OFF_BASIS);

  hipLaunchKernelGGL(k_basis, dim3(314), dim3(256), 0, stream, sdirs, pdirs, basis);
  hipLaunchKernelGGL(k_sj_part, dim3(NSJB), dim3(256), 0, stream, sdirs, vtemp, Jr, part);
  hipLaunchKernelGGL(k_sj_reduce, dim3(9), dim3(256), 0, stream, part, SJ);
  hipLaunchKernelGGL(k_jts, dim3(128), dim3(256), 0, stream, shp, expr, SJ, Jts);
  hipLaunchKernelGGL(k_bext_bf, dim3(768), dim3(256), 0, stream, shp, expr, bb);
  hipLaunchKernelGGL(k_pose, dim3(8), dim3(256), 0, stream, pose, Jts, bb, A, out);
  hipLaunchKernelGGL(k_main, dim3(32, 314), dim3(512), 0, stream,
                     basis, bb, A, lw, vtemp, out);
}

// Round 11
// 119.735 us; speedup vs baseline: 1.4176x; 1.1715x over previous
//
#include <hip/hip_runtime.h>
#include <hip/hip_bf16.h>
#include <math.h>

#define B_N 2048
#define V_N 5023
#define V3_N 15069
#define NSJB 157
#define CHUNK 32

typedef float f32x4 __attribute__((ext_vector_type(4)));
typedef short short8 __attribute__((ext_vector_type(8)));

static __device__ __forceinline__ ushort f2bf(float f) {
  __hip_bfloat16 h = __float2bfloat16(f);
  return *reinterpret_cast<ushort*>(&h);
}

// ================= L1: fused independent prologue =================
// blocks [0,314): basis transpose; [314,471): SJ partials; [471,1239): bext bf16
__global__ __launch_bounds__(256) void k_pre(const float* __restrict__ sdirs,
                                             const float* __restrict__ pdirs,
                                             const float* __restrict__ vtemp,
                                             const float* __restrict__ Jr,
                                             const float* __restrict__ shp,
                                             const float* __restrict__ expr,
                                             ushort* __restrict__ basis,
                                             float* __restrict__ part,
                                             ushort* __restrict__ bb) {
  __shared__ float Sh[16][452];
  __shared__ float Pd[36][48];
  int t = threadIdx.x, blk = blockIdx.x;
  if (blk < 314) {
    // ---- basis: [V][3][150]+pdirs -> bf16 [4v+c][192] ----
    int bx = blk, v0 = bx * 16;
    for (int idx = t; idx < 16 * 450; idx += 256) {
      int r = idx / 450, c = idx - r * 450;
      int v = v0 + r;
      Sh[r][c] = (v < V_N) ? sdirs[(size_t)v * 450 + c] : 0.0f;
    }
    for (int idx = t; idx < 36 * 48; idx += 256) {
      int p = idx / 48, c = idx - p * 48;
      int v3 = v0 * 3 + c;
      Pd[p][c] = (v3 < V3_N) ? pdirs[(size_t)p * V3_N + v3] : 0.0f;
    }
    __syncthreads();
    for (int idx = t; idx < 64 * 96; idx += 256) {
      int row = idx / 96, kp = idx - row * 96;
      int vl = row >> 2, c = row & 3;
      int k0 = kp * 2;
      float f0 = 0.0f, f1 = 0.0f;
      if (c < 3) {
        if (k0 < 150) {
          f0 = Sh[vl][c * 150 + k0];
          f1 = Sh[vl][c * 150 + k0 + 1];
        } else if (k0 < 186) {
          f0 = Pd[k0 - 150][vl * 3 + c];
          f1 = Pd[k0 - 149][vl * 3 + c];
        }
      }
      uint u = (uint)f2bf(f0) | ((uint)f2bf(f1) << 16);
      ((uint*)basis)[(size_t)(bx * 64 + row) * 96 + kp] = u;
    }
  } else if (blk < 314 + NSJB) {
    // ---- SJ partials ----
    float (*JrL)[CHUNK] = (float(*)[CHUNK]) & Sh[0][0];
    int bk = blk - 314;
    int vstart = bk * CHUNK;
    int cnt = min(CHUNK, V_N - vstart);
    for (int idx = t; idx < 5 * CHUNK; idx += 256) {
      int j = idx / CHUNK, vi = idx % CHUNK;
      JrL[j][vi] = (vi < cnt) ? Jr[j * V_N + vstart + vi] : 0.0f;
    }
    __syncthreads();
    float acc0[5] = {0, 0, 0, 0, 0}, acc1[5] = {0, 0, 0, 0, 0};
    int c0 = t, c1 = t + 256;
#pragma unroll 4
    for (int vi = 0; vi < CHUNK; ++vi) {
      int v = min(vstart + vi, V_N - 1);
      float val0 = sdirs[(size_t)v * 450 + c0];
      float val1 = 0.0f;
      if (c1 < 450) val1 = sdirs[(size_t)v * 450 + c1];
      else if (c1 < 453) val1 = vtemp[(size_t)v * 3 + (c1 - 450)];
#pragma unroll
      for (int j = 0; j < 5; ++j) {
        float w = JrL[j][vi];
        acc0[j] = fmaf(w, val0, acc0[j]);
        acc1[j] = fmaf(w, val1, acc1[j]);
      }
    }
    float* prow = part + (size_t)bk * 2280;
#pragma unroll
    for (int j = 0; j < 5; ++j) {
      prow[j * 456 + c0] = acc0[j];
      if (c1 < 453) prow[j * 456 + c1] = acc1[j];
    }
  } else {
    // ---- bext bf16 (cols 0..149; zero 150..191) ----
    int idx = (blk - 314 - NSJB) * 256 + t;  // 2048*96 uints
    int b = idx / 96, cp = idx - b * 96;
    int c0 = cp * 2;
    float f0 = 0.0f, f1 = 0.0f;
    if (c0 < 100) {
      f0 = shp[(size_t)b * 100 + c0];
      f1 = shp[(size_t)b * 100 + c0 + 1];
    } else if (c0 < 150) {
      f0 = expr[(size_t)b * 50 + (c0 - 100)];
      f1 = expr[(size_t)b * 50 + (c0 - 99)];
    }
    ((uint*)bb)[idx] = (uint)f2bf(f0) | ((uint)f2bf(f1) << 16);
  }
}

// ================= L2: reduce SJ partials =================
__global__ void k_sj_reduce(const float* __restrict__ part, float* __restrict__ SJ) {
  int id = blockIdx.x * 256 + threadIdx.x;
  if (id >= 2280) return;
  int c = id % 456;
  if (c >= 453) return;
  float s = 0.0f;
  for (int bk = 0; bk < NSJB; ++bk) s += part[(size_t)bk * 2280 + id];
  SJ[id] = s;
}

// ================= L3: fused Jts + pose (parallel dots, then chain) =================
// 128 blocks x 256 threads = 16 batches/block x 16 threads/batch.
__global__ __launch_bounds__(256) void k_jpose(const float* __restrict__ shp,
                                               const float* __restrict__ expr,
                                               const float* __restrict__ SJ,
                                               const float* __restrict__ pose,
                                               ushort* __restrict__ bb,
                                               float* __restrict__ A,
                                               float* __restrict__ out) {
  __shared__ float JtL[16][16];  // [group][jk] (15 used)
  int t = threadIdx.x;
  int g = t >> 4, r = t & 15;
  int b = blockIdx.x * 16 + g;
  // --- parallel Jts: thread r computes jk=r (r<15) ---
  if (r < 15) {
    int j = r / 3, k = r - j * 3;
    const float* SJr = SJ + j * 456;
    float acc = SJr[450 + k];
    const float* srow = shp + (size_t)b * 100;
    const float* erow = expr + (size_t)b * 50;
    for (int l = 0; l < 100; ++l) acc = fmaf(srow[l], SJr[k * 150 + l], acc);
    for (int l = 0; l < 50; ++l) acc = fmaf(erow[l], SJr[k * 150 + 100 + l], acc);
    JtL[g][r] = acc;
  }
  __syncthreads();
  if (r != 0) return;
  // --- lane-0-of-group: Rodrigues + chain + outputs ---
  float R[5][3][3];
#pragma unroll
  for (int j = 0; j < 5; ++j) {
    float rx = pose[(size_t)b * 15 + j * 3 + 0];
    float ry = pose[(size_t)b * 15 + j * 3 + 1];
    float rz = pose[(size_t)b * 15 + j * 3 + 2];
    float sx = rx + 1e-8f, sy = ry + 1e-8f, sz = rz + 1e-8f;
    float ang = sqrtf(sx * sx + sy * sy + sz * sz);
    float inv = 1.0f / ang;
    float ux = rx * inv, uy = ry * inv, uz = rz * inv;
    float c = cosf(ang), s = sinf(ang), omc = 1.0f - c;
    float K[3][3] = {{0.0f, -uz, uy}, {uz, 0.0f, -ux}, {-uy, ux, 0.0f}};
#pragma unroll
    for (int m = 0; m < 3; ++m)
#pragma unroll
      for (int n = 0; n < 3; ++n) {
        float k2 = 0.0f;
#pragma unroll
        for (int q = 0; q < 3; ++q) k2 += K[m][q] * K[q][n];
        R[j][m][n] = ((m == n) ? 1.0f : 0.0f) + s * K[m][n] + omc * k2;
      }
  }
  {
    float pf[36];
#pragma unroll
    for (int j = 1; j < 5; ++j)
#pragma unroll
      for (int m = 0; m < 3; ++m)
#pragma unroll
        for (int n = 0; n < 3; ++n)
          pf[(j - 1) * 9 + m * 3 + n] = R[j][m][n] - ((m == n) ? 1.0f : 0.0f);
    uint* bbu = (uint*)bb + (size_t)b * 96 + 75;
#pragma unroll
    for (int q = 0; q < 18; ++q)
      bbu[q] = (uint)f2bf(pf[2 * q]) | ((uint)f2bf(pf[2 * q + 1]) << 16);
  }
  float Jt[5][3];
#pragma unroll
  for (int j = 0; j < 5; ++j)
#pragma unroll
    for (int k = 0; k < 3; ++k) Jt[j][k] = JtL[g][j * 3 + k];
  const int par[5] = {0, 0, 1, 1, 1};
  float rel[5][3];
#pragma unroll
  for (int k = 0; k < 3; ++k) rel[0][k] = Jt[0][k];
#pragma unroll
  for (int j = 1; j < 5; ++j)
#pragma unroll
    for (int k = 0; k < 3; ++k) rel[j][k] = Jt[j][k] - Jt[par[j]][k];
  float Rg[5][3][3], tg[5][3];
#pragma unroll
  for (int m = 0; m < 3; ++m) {
#pragma unroll
    for (int n = 0; n < 3; ++n) Rg[0][m][n] = R[0][m][n];
    tg[0][m] = rel[0][m];
  }
#pragma unroll
  for (int j = 1; j < 5; ++j) {
    int p = par[j];
#pragma unroll
    for (int m = 0; m < 3; ++m) {
      float t2 = tg[p][m];
#pragma unroll
      for (int n = 0; n < 3; ++n) {
        float s = 0.0f;
#pragma unroll
        for (int q = 0; q < 3; ++q) s = fmaf(Rg[p][m][q], R[j][q][n], s);
        Rg[j][m][n] = s;
        t2 = fmaf(Rg[p][m][n], rel[j][n], t2);
      }
      tg[j][m] = t2;
    }
  }
#pragma unroll
  for (int j = 0; j < 5; ++j)
#pragma unroll
    for (int k = 0; k < 3; ++k)
      out[(size_t)B_N * V_N * 3 + ((size_t)b * 5 + j) * 3 + k] = tg[j][k];
  float Af[5][12];
#pragma unroll
  for (int j = 0; j < 5; ++j)
#pragma unroll
    for (int m = 0; m < 3; ++m) {
      float tj = 0.0f;
#pragma unroll
      for (int n = 0; n < 3; ++n) {
        Af[j][m * 4 + n] = Rg[j][m][n];
        tj = fmaf(Rg[j][m][n], Jt[j][n], tj);
      }
      Af[j][m * 4 + 3] = tg[j][m] - tj;
    }
  float* Ab = A + (size_t)b * 64;
#pragma unroll
  for (int q = 0; q < 12; ++q) Ab[q] = Af[0][q];
#pragma unroll
  for (int j = 1; j < 5; ++j)
#pragma unroll
    for (int q = 0; q < 12; ++q) Ab[j * 12 + q] = Af[j][q] - Af[0][q];
}

// ================= L4: MFMA GEMM + fused skinning (R9-proven) =================
// grid (32 batch-tiles FAST, 314 vertex-tiles slow). 8 waves: 4(M) x 2(N).
__global__ __launch_bounds__(512, 4) void k_main(const ushort* __restrict__ basis,
                                                 const ushort* __restrict__ bb,
                                                 const float* __restrict__ Amat,
                                                 const float* __restrict__ lw,
                                                 const float* __restrict__ vtemp,
                                                 float* __restrict__ out) {
  __shared__ alignas(16) ushort AL[64 * 200];
  __shared__ alignas(16) ushort BL[64 * 200];
  __shared__ alignas(16) float AmL[64 * 68];  // delta-form rel transforms
  int t = threadIdx.x;
  int bx = blockIdx.y;  // vertex tile (slow)
  int by = blockIdx.x;  // batch tile (fast -> basis tile L2-reused by 32 blocks)
  int b0 = by * 64;
#pragma unroll
  for (int i = 0; i < 3; ++i) {
    int c = t + i * 512;
    int r = c / 24, k = (c % 24) * 8;
    *(short8*)(&AL[r * 200 + k]) = *(const short8*)(&basis[((size_t)bx * 64 + r) * 192 + k]);
    *(short8*)(&BL[r * 200 + k]) = *(const short8*)(&bb[((size_t)(b0 + r)) * 192 + k]);
  }
#pragma unroll
  for (int i = 0; i < 2; ++i) {
    int c = t + i * 512;
    int r = c / 16, q = (c % 16) * 4;
    *(f32x4*)(&AmL[r * 68 + q]) = *(const f32x4*)(&Amat[((size_t)(b0 + r)) * 64 + q]);
  }
  __syncthreads();
  int lane = t & 63;
  int w = __builtin_amdgcn_readfirstlane(t >> 6);
  int wm = w >> 1, wn = w & 1;
  int lm = lane & 15, g = lane >> 4;
  f32x4 acc0 = {0.f, 0.f, 0.f, 0.f}, acc1 = {0.f, 0.f, 0.f, 0.f};
  const int arow = (wm * 16 + lm) * 200;
  const int brow0 = (wn * 32 + lm) * 200;
  const int brow1 = (wn * 32 + 16 + lm) * 200;
#pragma unroll
  for (int ks = 0; ks < 6; ++ks) {
    int k = ks * 32 + 8 * g;
    short8 af = *(const short8*)(&AL[arow + k]);
    short8 bf0 = *(const short8*)(&BL[brow0 + k]);
    short8 bf1 = *(const short8*)(&BL[brow1 + k]);
    acc0 = __builtin_amdgcn_mfma_f32_16x16x32_bf16(af, bf0, acc0, 0, 0, 0);
    acc1 = __builtin_amdgcn_mfma_f32_16x16x32_bf16(af, bf1, acc1, 0, 0, 0);
  }
  int v = bx * 16 + wm * 4 + g;
  bool valid = v < V_N;
  int vv = valid ? v : 0;
  float wv[4];
#pragma unroll
  for (int j = 0; j < 4; ++j) wv[j] = lw[(size_t)vv * 5 + 1 + j];
  float vt0 = vtemp[(size_t)vv * 3 + 0];
  float vt1 = vtemp[(size_t)vv * 3 + 1];
  float vt2 = vtemp[(size_t)vv * 3 + 2];
#pragma unroll
  for (int ni = 0; ni < 2; ++ni) {
    f32x4 p = ni ? acc1 : acc0;
    int bl = wn * 32 + ni * 16 + lm;
    const float* Ar = &AmL[bl * 68];
    f32x4 T0 = *(const f32x4*)(Ar + 0);
    f32x4 T1 = *(const f32x4*)(Ar + 4);
    f32x4 T2 = *(const f32x4*)(Ar + 8);
#pragma unroll
    for (int j = 1; j < 5; ++j) {
      f32x4 d0 = *(const f32x4*)(Ar + j * 12 + 0);
      f32x4 d1 = *(const f32x4*)(Ar + j * 12 + 4);
      f32x4 d2 = *(const f32x4*)(Ar + j * 12 + 8);
      float wjv = wv[j - 1];
#pragma unroll
      for (int c = 0; c < 4; ++c) {
        T0[c] = fmaf(wjv, d0[c], T0[c]);
        T1[c] = fmaf(wjv, d1[c], T1[c]);
        T2[c] = fmaf(wjv, d2[c], T2[c]);
      }
    }
    float x = p[0] + vt0, y = p[1] + vt1, z = p[2] + vt2;
    float ox = fmaf(T0[0], x, fmaf(T0[1], y, fmaf(T0[2], z, T0[3])));
    float oy = fmaf(T1[0], x, fmaf(T1[1], y, fmaf(T1[2], z, T1[3])));
    float oz = fmaf(T2[0], x, fmaf(T2[1], y, fmaf(T2[2], z, T2[3])));
    if (valid) {
      size_t o = ((size_t)(b0 + bl)) * V3_N + (size_t)v * 3;
      out[o + 0] = ox;
      out[o + 1] = oy;
      out[o + 2] = oz;
    }
  }
}

extern "C" void kernel_launch(void* const* d_in, const int* in_sizes, int n_in,
                              void* d_out, int out_size, void* d_ws, size_t ws_size,
                              hipStream_t stream) {
  const float* shp = (const float*)d_in[0];
  const float* expr = (const float*)d_in[1];
  const float* pose = (const float*)d_in[2];
  const float* vtemp = (const float*)d_in[3];
  const float* sdirs = (const float*)d_in[4];
  const float* pdirs = (const float*)d_in[5];
  const float* Jr = (const float*)d_in[6];
  const float* lw = (const float*)d_in[7];
  float* out = (float*)d_out;
  float* wsf = (float*)d_ws;

  // workspace layout (float slots)
  const size_t OFF_PART = 0;         // 157*2280 = 357,960
  const size_t OFF_SJ = 358400;      // 2,280
  const size_t OFF_A = 786688;       // 131,072
  const size_t OFF_BB = 917760;      // bf16 2048*192 -> 196,608 f32 slots
  const size_t OFF_BASIS = 1114368;  // bf16 20096*192 -> 1,929,216 f32 slots (ends 3,043,584)
  float* part = wsf + OFF_PART;
  float* SJ = wsf + OFF_SJ;
  float* A = wsf + OFF_A;
  ushort* bb = (ushort*)(wsf + OFF_BB);
  ushort* basis = (ushort*)(wsf + OFF_BASIS);

  hipLaunchKernelGGL(k_pre, dim3(314 + NSJB + 768), dim3(256), 0, stream,
                     sdirs, pdirs, vtemp, Jr, shp, expr, basis, part, bb);
  hipLaunchKernelGGL(k_sj_reduce, dim3(9), dim3(256), 0, stream, part, SJ);
  hipLaunchKernelGGL(k_jpose, dim3(128), dim3(256), 0, stream,
                     shp, expr, SJ, pose, bb, A, out);
  hipLaunchKernelGGL(k_main, dim3(32, 314), dim3(512), 0, stream,
                     basis, bb, A, lw, vtemp, out);
}

// Round 12
// 111.710 us; speedup vs baseline: 1.5195x; 1.0718x over previous
//
#include <hip/hip_runtime.h>
#include <hip/hip_bf16.h>
#include <math.h>

#define B_N 2048
#define V_N 5023
#define V3_N 15069
#define NSJB 157
#define CHUNK 32

typedef float f32x4 __attribute__((ext_vector_type(4)));
typedef short short8 __attribute__((ext_vector_type(8)));

static __device__ __forceinline__ ushort f2bf(float f) {
  __hip_bfloat16 h = __float2bfloat16(f);
  return *reinterpret_cast<ushort*>(&h);
}

// ================= L1: fused independent prologue =================
// blocks [0,314): basis transpose; [314,471): SJ partials (atomic); [471,1239): bext bf16
__global__ __launch_bounds__(256) void k_pre(const float* __restrict__ sdirs,
                                             const float* __restrict__ pdirs,
                                             const float* __restrict__ vtemp,
                                             const float* __restrict__ Jr,
                                             const float* __restrict__ shp,
                                             const float* __restrict__ expr,
                                             ushort* __restrict__ basis,
                                             float* __restrict__ SJ,
                                             ushort* __restrict__ bb) {
  __shared__ float Sh[16][452];
  __shared__ float Pd[36][48];
  int t = threadIdx.x, blk = blockIdx.x;
  if (blk < 314) {
    // ---- basis: [V][3][150]+pdirs -> bf16 [4v+c][192] ----
    int bx = blk, v0 = bx * 16;
    for (int idx = t; idx < 16 * 450; idx += 256) {
      int r = idx / 450, c = idx - r * 450;
      int v = v0 + r;
      Sh[r][c] = (v < V_N) ? sdirs[(size_t)v * 450 + c] : 0.0f;
    }
    for (int idx = t; idx < 36 * 48; idx += 256) {
      int p = idx / 48, c = idx - p * 48;
      int v3 = v0 * 3 + c;
      Pd[p][c] = (v3 < V3_N) ? pdirs[(size_t)p * V3_N + v3] : 0.0f;
    }
    __syncthreads();
    for (int idx = t; idx < 64 * 96; idx += 256) {
      int row = idx / 96, kp = idx - row * 96;
      int vl = row >> 2, c = row & 3;
      int k0 = kp * 2;
      float f0 = 0.0f, f1 = 0.0f;
      if (c < 3) {
        if (k0 < 150) {
          f0 = Sh[vl][c * 150 + k0];
          f1 = Sh[vl][c * 150 + k0 + 1];
        } else if (k0 < 186) {
          f0 = Pd[k0 - 150][vl * 3 + c];
          f1 = Pd[k0 - 149][vl * 3 + c];
        }
      }
      uint u = (uint)f2bf(f0) | ((uint)f2bf(f1) << 16);
      ((uint*)basis)[(size_t)(bx * 64 + row) * 96 + kp] = u;
    }
  } else if (blk < 314 + NSJB) {
    // ---- SJ partials, accumulated via atomics ----
    float (*JrL)[CHUNK] = (float(*)[CHUNK]) & Sh[0][0];
    int bk = blk - 314;
    int vstart = bk * CHUNK;
    int cnt = min(CHUNK, V_N - vstart);
    for (int idx = t; idx < 5 * CHUNK; idx += 256) {
      int j = idx / CHUNK, vi = idx % CHUNK;
      JrL[j][vi] = (vi < cnt) ? Jr[j * V_N + vstart + vi] : 0.0f;
    }
    __syncthreads();
    float acc0[5] = {0, 0, 0, 0, 0}, acc1[5] = {0, 0, 0, 0, 0};
    int c0 = t, c1 = t + 256;
#pragma unroll 4
    for (int vi = 0; vi < CHUNK; ++vi) {
      int v = min(vstart + vi, V_N - 1);
      float val0 = sdirs[(size_t)v * 450 + c0];
      float val1 = 0.0f;
      if (c1 < 450) val1 = sdirs[(size_t)v * 450 + c1];
      else if (c1 < 453) val1 = vtemp[(size_t)v * 3 + (c1 - 450)];
#pragma unroll
      for (int j = 0; j < 5; ++j) {
        float w = JrL[j][vi];
        acc0[j] = fmaf(w, val0, acc0[j]);
        acc1[j] = fmaf(w, val1, acc1[j]);
      }
    }
#pragma unroll
    for (int j = 0; j < 5; ++j) {
      atomicAdd(&SJ[j * 456 + c0], acc0[j]);
      if (c1 < 453) atomicAdd(&SJ[j * 456 + c1], acc1[j]);
    }
  } else {
    // ---- bext bf16 (cols 0..149; zero 150..191) ----
    int idx = (blk - 314 - NSJB) * 256 + t;  // 2048*96 uints
    int b = idx / 96, cp = idx - b * 96;
    int c0 = cp * 2;
    float f0 = 0.0f, f1 = 0.0f;
    if (c0 < 100) {
      f0 = shp[(size_t)b * 100 + c0];
      f1 = shp[(size_t)b * 100 + c0 + 1];
    } else if (c0 < 150) {
      f0 = expr[(size_t)b * 50 + (c0 - 100)];
      f1 = expr[(size_t)b * 50 + (c0 - 99)];
    }
    ((uint*)bb)[idx] = (uint)f2bf(f0) | ((uint)f2bf(f1) << 16);
  }
}

// ================= L2: fused Jts + pose (parallel dots, then chain) =================
// 128 blocks x 256 threads = 16 batches/block x 16 threads/batch.
__global__ __launch_bounds__(256) void k_jpose(const float* __restrict__ shp,
                                               const float* __restrict__ expr,
                                               const float* __restrict__ SJ,
                                               const float* __restrict__ pose,
                                               ushort* __restrict__ bb,
                                               float* __restrict__ A,
                                               float* __restrict__ out) {
  __shared__ float JtL[16][16];  // [group][jk] (15 used)
  int t = threadIdx.x;
  int g = t >> 4, r = t & 15;
  int b = blockIdx.x * 16 + g;
  if (r < 15) {
    int j = r / 3, k = r - j * 3;
    const float* SJr = SJ + j * 456;
    float acc = SJr[450 + k];
    const float* srow = shp + (size_t)b * 100;
    const float* erow = expr + (size_t)b * 50;
    for (int l = 0; l < 100; ++l) acc = fmaf(srow[l], SJr[k * 150 + l], acc);
    for (int l = 0; l < 50; ++l) acc = fmaf(erow[l], SJr[k * 150 + 100 + l], acc);
    JtL[g][r] = acc;
  }
  __syncthreads();
  if (r != 0) return;
  float R[5][3][3];
#pragma unroll
  for (int j = 0; j < 5; ++j) {
    float rx = pose[(size_t)b * 15 + j * 3 + 0];
    float ry = pose[(size_t)b * 15 + j * 3 + 1];
    float rz = pose[(size_t)b * 15 + j * 3 + 2];
    float sx = rx + 1e-8f, sy = ry + 1e-8f, sz = rz + 1e-8f;
    float ang = sqrtf(sx * sx + sy * sy + sz * sz);
    float inv = 1.0f / ang;
    float ux = rx * inv, uy = ry * inv, uz = rz * inv;
    float c = cosf(ang), s = sinf(ang), omc = 1.0f - c;
    float K[3][3] = {{0.0f, -uz, uy}, {uz, 0.0f, -ux}, {-uy, ux, 0.0f}};
#pragma unroll
    for (int m = 0; m < 3; ++m)
#pragma unroll
      for (int n = 0; n < 3; ++n) {
        float k2 = 0.0f;
#pragma unroll
        for (int q = 0; q < 3; ++q) k2 += K[m][q] * K[q][n];
        R[j][m][n] = ((m == n) ? 1.0f : 0.0f) + s * K[m][n] + omc * k2;
      }
  }
  {
    float pf[36];
#pragma unroll
    for (int j = 1; j < 5; ++j)
#pragma unroll
      for (int m = 0; m < 3; ++m)
#pragma unroll
        for (int n = 0; n < 3; ++n)
          pf[(j - 1) * 9 + m * 3 + n] = R[j][m][n] - ((m == n) ? 1.0f : 0.0f);
    uint* bbu = (uint*)bb + (size_t)b * 96 + 75;
#pragma unroll
    for (int q = 0; q < 18; ++q)
      bbu[q] = (uint)f2bf(pf[2 * q]) | ((uint)f2bf(pf[2 * q + 1]) << 16);
  }
  float Jt[5][3];
#pragma unroll
  for (int j = 0; j < 5; ++j)
#pragma unroll
    for (int k = 0; k < 3; ++k) Jt[j][k] = JtL[g][j * 3 + k];
  const int par[5] = {0, 0, 1, 1, 1};
  float rel[5][3];
#pragma unroll
  for (int k = 0; k < 3; ++k) rel[0][k] = Jt[0][k];
#pragma unroll
  for (int j = 1; j < 5; ++j)
#pragma unroll
    for (int k = 0; k < 3; ++k) rel[j][k] = Jt[j][k] - Jt[par[j]][k];
  float Rg[5][3][3], tg[5][3];
#pragma unroll
  for (int m = 0; m < 3; ++m) {
#pragma unroll
    for (int n = 0; n < 3; ++n) Rg[0][m][n] = R[0][m][n];
    tg[0][m] = rel[0][m];
  }
#pragma unroll
  for (int j = 1; j < 5; ++j) {
    int p = par[j];
#pragma unroll
    for (int m = 0; m < 3; ++m) {
      float t2 = tg[p][m];
#pragma unroll
      for (int n = 0; n < 3; ++n) {
        float s = 0.0f;
#pragma unroll
        for (int q = 0; q < 3; ++q) s = fmaf(Rg[p][m][q], R[j][q][n], s);
        Rg[j][m][n] = s;
        t2 = fmaf(Rg[p][m][n], rel[j][n], t2);
      }
      tg[j][m] = t2;
    }
  }
#pragma unroll
  for (int j = 0; j < 5; ++j)
#pragma unroll
    for (int k = 0; k < 3; ++k)
      out[(size_t)B_N * V_N * 3 + ((size_t)b * 5 + j) * 3 + k] = tg[j][k];
  float Af[5][12];
#pragma unroll
  for (int j = 0; j < 5; ++j)
#pragma unroll
    for (int m = 0; m < 3; ++m) {
      float tj = 0.0f;
#pragma unroll
      for (int n = 0; n < 3; ++n) {
        Af[j][m * 4 + n] = Rg[j][m][n];
        tj = fmaf(Rg[j][m][n], Jt[j][n], tj);
      }
      Af[j][m * 4 + 3] = tg[j][m] - tj;
    }
  float* Ab = A + (size_t)b * 64;
#pragma unroll
  for (int q = 0; q < 12; ++q) Ab[q] = Af[0][q];
#pragma unroll
  for (int j = 1; j < 5; ++j)
#pragma unroll
    for (int q = 0; q < 12; ++q) Ab[j * 12 + q] = Af[j][q] - Af[0][q];
}

// ================= L3: MFMA GEMM + fused skinning =================
// AL/BL: 64 rows x 24 16B-chunks, XOR-swizzled (chunk ^= row&7). AmL overlaps AL post-k-loop.
// grid (32 batch-tiles FAST, 314 vertex-tiles slow). 8 waves: 4(M) x 2(N). 3 blocks/CU.
__global__ __launch_bounds__(512, 6) void k_main(const ushort* __restrict__ basis,
                                                 const ushort* __restrict__ bb,
                                                 const float* __restrict__ Amat,
                                                 const float* __restrict__ lw,
                                                 const float* __restrict__ vtemp,
                                                 float* __restrict__ out) {
  __shared__ alignas(16) ushort AL[64 * 192];  // 24.6 KB; reused as AmL post-k-loop
  __shared__ alignas(16) ushort BL[64 * 192];  // 24.6 KB
  float* AmL = (float*)AL;                     // [64][68] = 17.4 KB fits in AL
  int t = threadIdx.x;
  int bx = blockIdx.y;  // vertex tile (slow)
  int by = blockIdx.x;  // batch tile (fast -> basis tile L2-reused by 32 blocks)
  int b0 = by * 64;
#pragma unroll
  for (int i = 0; i < 3; ++i) {
    int c = t + i * 512;
    int r = c / 24, kb = c % 24;
    int dst = (r * 24 + (kb ^ (r & 7))) * 8;
    *(short8*)(&AL[dst]) = *(const short8*)(&basis[((size_t)bx * 64 + r) * 192 + kb * 8]);
    *(short8*)(&BL[dst]) = *(const short8*)(&bb[((size_t)(b0 + r)) * 192 + kb * 8]);
  }
  __syncthreads();
  int lane = t & 63;
  int w = __builtin_amdgcn_readfirstlane(t >> 6);
  int wm = w >> 1, wn = w & 1;
  int lm = lane & 15, g = lane >> 4;
  f32x4 acc0 = {0.f, 0.f, 0.f, 0.f}, acc1 = {0.f, 0.f, 0.f, 0.f};
  const int ar = wm * 16 + lm;
  const int br0 = wn * 32 + lm;
  const int br1 = wn * 32 + 16 + lm;
#pragma unroll
  for (int ks = 0; ks < 6; ++ks) {
    int kb = ks * 4 + g;
    short8 af = *(const short8*)(&AL[(ar * 24 + (kb ^ (ar & 7))) * 8]);
    short8 bf0 = *(const short8*)(&BL[(br0 * 24 + (kb ^ (br0 & 7))) * 8]);
    short8 bf1 = *(const short8*)(&BL[(br1 * 24 + (kb ^ (br1 & 7))) * 8]);
    acc0 = __builtin_amdgcn_mfma_f32_16x16x32_bf16(af, bf0, acc0, 0, 0, 0);
    acc1 = __builtin_amdgcn_mfma_f32_16x16x32_bf16(af, bf1, acc1, 0, 0, 0);
  }
  int v = bx * 16 + wm * 4 + g;
  bool valid = v < V_N;
  int vv = valid ? v : 0;
  float wv[4];
#pragma unroll
  for (int j = 0; j < 4; ++j) wv[j] = lw[(size_t)vv * 5 + 1 + j];
  float vt0 = vtemp[(size_t)vv * 3 + 0];
  float vt1 = vtemp[(size_t)vv * 3 + 1];
  float vt2 = vtemp[(size_t)vv * 3 + 2];
  __syncthreads();  // AL reads done; reuse as AmL
#pragma unroll
  for (int i = 0; i < 2; ++i) {
    int c = t + i * 512;
    int r = c / 16, q = (c % 16) * 4;
    *(f32x4*)(&AmL[r * 68 + q]) = *(const f32x4*)(&Amat[((size_t)(b0 + r)) * 64 + q]);
  }
  __syncthreads();
#pragma unroll
  for (int ni = 0; ni < 2; ++ni) {
    f32x4 p = ni ? acc1 : acc0;
    int bl = wn * 32 + ni * 16 + lm;
    const float* Ar = &AmL[bl * 68];
    f32x4 T0 = *(const f32x4*)(Ar + 0);
    f32x4 T1 = *(const f32x4*)(Ar + 4);
    f32x4 T2 = *(const f32x4*)(Ar + 8);
#pragma unroll
    for (int j = 1; j < 5; ++j) {
      f32x4 d0 = *(const f32x4*)(Ar + j * 12 + 0);
      f32x4 d1 = *(const f32x4*)(Ar + j * 12 + 4);
      f32x4 d2 = *(const f32x4*)(Ar + j * 12 + 8);
      float wjv = wv[j - 1];
#pragma unroll
      for (int c = 0; c < 4; ++c) {
        T0[c] = fmaf(wjv, d0[c], T0[c]);
        T1[c] = fmaf(wjv, d1[c], T1[c]);
        T2[c] = fmaf(wjv, d2[c], T2[c]);
      }
    }
    float x = p[0] + vt0, y = p[1] + vt1, z = p[2] + vt2;
    float ox = fmaf(T0[0], x, fmaf(T0[1], y, fmaf(T0[2], z, T0[3])));
    float oy = fmaf(T1[0], x, fmaf(T1[1], y, fmaf(T1[2], z, T1[3])));
    float oz = fmaf(T2[0], x, fmaf(T2[1], y, fmaf(T2[2], z, T2[3])));
    if (valid) {
      size_t o = ((size_t)(b0 + bl)) * V3_N + (size_t)v * 3;
      out[o + 0] = ox;
      out[o + 1] = oy;
      out[o + 2] = oz;
    }
  }
}

extern "C" void kernel_launch(void* const* d_in, const int* in_sizes, int n_in,
                              void* d_out, int out_size, void* d_ws, size_t ws_size,
                              hipStream_t stream) {
  const float* shp = (const float*)d_in[0];
  const float* expr = (const float*)d_in[1];
  const float* pose = (const float*)d_in[2];
  const float* vtemp = (const float*)d_in[3];
  const float* sdirs = (const float*)d_in[4];
  const float* pdirs = (const float*)d_in[5];
  const float* Jr = (const float*)d_in[6];
  const float* lw = (const float*)d_in[7];
  float* out = (float*)d_out;
  float* wsf = (float*)d_ws;

  // workspace layout (float slots)
  const size_t OFF_SJ = 358400;      // 2,280
  const size_t OFF_A = 786688;       // 131,072
  const size_t OFF_BB = 917760;      // bf16 2048*192 -> 196,608 f32 slots
  const size_t OFF_BASIS = 1114368;  // bf16 20096*192 -> 1,929,216 f32 slots (ends 3,043,584)
  float* SJ = wsf + OFF_SJ;
  float* A = wsf + OFF_A;
  ushort* bb = (ushort*)(wsf + OFF_BB);
  ushort* basis = (ushort*)(wsf + OFF_BASIS);

  hipMemsetAsync(SJ, 0, 2280 * sizeof(float), stream);
  hipLaunchKernelGGL(k_pre, dim3(314 + NSJB + 768), dim3(256), 0, stream,
                     sdirs, pdirs, vtemp, Jr, shp, expr, basis, SJ, bb);
  hipLaunchKernelGGL(k_jpose, dim3(128), dim3(256), 0, stream,
                     shp, expr, SJ, pose, bb, A, out);
  hipLaunchKernelGGL(k_main, dim3(32, 314), dim3(512), 0, stream,
                     basis, bb, A, lw, vtemp, out);
}